// Round 1
// 382.834 us; speedup vs baseline: 1.0037x; 1.0037x over previous
//
#include <hip/hip_runtime.h>
#include <math.h>

#define D_DIM 4096
#define E_DIM 64
#define TM 64                    // tokens per block
#define KSPLIT 4
#define KPART (D_DIM / KSPLIT)   // 1024
#define CHK 64                   // k per chunk
#define NCH (KPART / CHK)        // 16
#define WROW 72                  // padded k-stride (elements) for W LDS rows
#define WSCALE 1024.0f           // keep f16 split residuals of W out of subnormal range
#define ISCALE (1.0f / 1024.0f)

typedef __attribute__((ext_vector_type(8))) __fp16 f16x8;
typedef __attribute__((ext_vector_type(2))) __fp16 f16x2;
typedef __attribute__((ext_vector_type(4))) float f32x4;

// 2-level f16 split: f = hi + lo + O(2^-20 rel). v_cvt_pkrtz packs 2 f32->2 f16 (RTZ).
__device__ inline void split2(const f32x4 a0, const f32x4 a1, f16x8& fh, f16x8& fl) {
    float f[8] = {a0[0], a0[1], a0[2], a0[3], a1[0], a1[1], a1[2], a1[3]};
    union { f16x8 v; f16x2 p[4]; } H, L;
    #pragma unroll
    for (int j = 0; j < 4; ++j) {
        const f16x2 h = __builtin_amdgcn_cvt_pkrtz(f[2*j], f[2*j+1]);
        const float r0 = f[2*j]     - (float)h[0];   // exact residual of truncation
        const float r1 = f[2*j + 1] - (float)h[1];
        H.p[j] = h;
        L.p[j] = __builtin_amdgcn_cvt_pkrtz(r0, r1);
    }
    fh = H.v; fl = L.v;
}

// ---------------- kernel 1: K-split MFMA GEMM, atomic partial-logit accumulate ----------------
__global__ __launch_bounds__(256, 4) void router_gemm(
    const float* __restrict__ hs,
    const float* __restrict__ W,
    float* __restrict__ logits,   // [nTok, 64], pre-zeroed
    int nTok)
{
    // double-buffered W staging: 2 levels x 2 buffers x 64x72 f16 = 36.9 KB (4 blocks/CU ok)
    __shared__ __fp16 wsh[2][E_DIM * WROW];
    __shared__ __fp16 wsl[2][E_DIM * WROW];

    const int tid  = threadIdx.x;
    const int lane = tid & 63;
    const int wv   = tid >> 6;                  // wave 0..3 -> token group
    const int part = blockIdx.x & (KSPLIT - 1);
    const int tb   = (blockIdx.x >> 2) * TM;
    const int kb   = part * KPART;

    const int l15 = lane & 15;                  // A: token within wave-tile; B: expert within tile
    const int lq  = lane >> 4;                  // k-quad (8 k's)

    // A fragments straight from global: lane holds A[m=l15][k=lq*8+j] (contiguous 32 B)
    const float* aptr = hs + (size_t)(tb + wv * 16 + l15) * D_DIM + kb + lq * 8;
    // W staging: thread covers expert we, 16 consecutive k (2 groups of 8)
    const int we = tid >> 2;
    const int wq = tid & 3;
    const float* wptr = W + (size_t)we * D_DIM + kb + wq * 16;

    f32x4 acc[4];
    #pragma unroll
    for (int t = 0; t < 4; ++t) acc[t] = (f32x4){0.f, 0.f, 0.f, 0.f};

    f32x4 ca[4], pa[4], wr[4];

    auto loadA = [&](int ch, f32x4* dst) {
        const float* p = aptr + ch * CHK;
        dst[0] = *(const f32x4*)(p);
        dst[1] = *(const f32x4*)(p + 4);
        dst[2] = *(const f32x4*)(p + 32);
        dst[3] = *(const f32x4*)(p + 36);
    };
    auto loadW = [&](int ch) {
        const float* p = wptr + ch * CHK;
        wr[0] = *(const f32x4*)(p);
        wr[1] = *(const f32x4*)(p + 4);
        wr[2] = *(const f32x4*)(p + 8);
        wr[3] = *(const f32x4*)(p + 12);
    };
    auto storeW = [&](int buf) {
        f16x8 h0, l0, h1, l1;
        split2(wr[0] * WSCALE, wr[1] * WSCALE, h0, l0);
        split2(wr[2] * WSCALE, wr[3] * WSCALE, h1, l1);
        const int base = we * WROW + wq * 16;
        *(f16x8*)&wsh[buf][base] = h0;  *(f16x8*)&wsh[buf][base + 8] = h1;  // ds_write_b128
        *(f16x8*)&wsl[buf][base] = l0;  *(f16x8*)&wsl[buf][base + 8] = l1;
    };
    auto compute = [&](const f32x4* a, int buf) {
        #pragma unroll
        for (int s = 0; s < 2; ++s) {
            f16x8 ah, al;
            split2(a[2 * s], a[2 * s + 1], ah, al);
            const int koff = s * 32 + lq * 8;
            #pragma unroll
            for (int t = 0; t < 4; ++t) {
                const int rb = (t * 16 + l15) * WROW + koff;
                const f16x8 bh = *(const f16x8*)&wsh[buf][rb];
                const f16x8 bl = *(const f16x8*)&wsl[buf][rb];
                acc[t] = __builtin_amdgcn_mfma_f32_16x16x32_f16(ah, bh, acc[t], 0, 0, 0);
                acc[t] = __builtin_amdgcn_mfma_f32_16x16x32_f16(ah, bl, acc[t], 0, 0, 0);
                acc[t] = __builtin_amdgcn_mfma_f32_16x16x32_f16(al, bh, acc[t], 0, 0, 0);
            }
        }
    };

    loadA(0, ca);
    loadW(0);
    storeW(0);
    __syncthreads();
    int buf = 0;
    #pragma unroll 1
    for (int ch = 0; ch < NCH; ++ch) {
        const bool last = (ch == NCH - 1);
        if (!last) {
            loadA(ch + 1, pa);              // in flight during compute
            loadW(ch + 1);                  // L2-resident, short latency
        }
        compute(ca, buf);
        if (!last) {
            storeW(buf ^ 1);                // write other buffer: no read/write race
            __syncthreads();                // next W chunk visible to all waves
            #pragma unroll
            for (int i = 0; i < 4; ++i) ca[i] = pa[i];
            buf ^= 1;
        }
    }

    // C/D layout: col(expert) = l15, row(token) = lq*4 + r; unscale the 2^10 W factor
    float* dst = logits + (size_t)(tb + wv * 16) * E_DIM;
    #pragma unroll
    for (int t = 0; t < 4; ++t)
        #pragma unroll
        for (int r = 0; r < 4; ++r)
            unsafeAtomicAdd(&dst[(size_t)(lq * 4 + r) * E_DIM + t * 16 + l15], acc[t][r] * ISCALE);
}

// ---------------- kernel 2: bias + softmax + top-2, LDS-free, 4 lanes/token ----------------
__global__ __launch_bounds__(256, 4) void router_epilogue(
    const float* __restrict__ bias,
    float* __restrict__ out,
    int nTok)
{
    const int tid = threadIdx.x;
    const int tok = blockIdx.x * 64 + (tid >> 2);
    const int g   = tid & 3;

    float* out_idx = out;
    float* out_val = out + (size_t)nTok * 2;
    float* sc      = out + (size_t)nTok * 4;

    float* src = sc + (size_t)tok * E_DIM + g * 16;
    float v[16];
    #pragma unroll
    for (int j = 0; j < 4; ++j) {
        const f32x4 x = *(const f32x4*)(src + j * 4);
        const f32x4 b = *(const f32x4*)(bias + g * 16 + j * 4);
        v[j * 4 + 0] = x[0] + b[0];
        v[j * 4 + 1] = x[1] + b[1];
        v[j * 4 + 2] = x[2] + b[2];
        v[j * 4 + 3] = x[3] + b[3];
    }

    // local top-2 (ascending index, strict > keeps lowest index)
    float b1 = -INFINITY, b2 = -INFINITY;
    int i1 = 0, i2 = 0;
    #pragma unroll
    for (int j = 0; j < 16; ++j) {
        const float x = v[j];
        const int idx = g * 16 + j;
        if (x > b1)      { b2 = b1; i2 = i1; b1 = x; i1 = idx; }
        else if (x > b2) { b2 = x; i2 = idx; }
    }
    // butterfly merge across the 4 lanes of this token
    #pragma unroll
    for (int d = 1; d <= 2; d <<= 1) {
        const float ob1 = __shfl_xor(b1, d);
        const int   oi1 = __shfl_xor(i1, d);
        const float ob2 = __shfl_xor(b2, d);
        const int   oi2 = __shfl_xor(i2, d);
        if (ob1 > b1 || (ob1 == b1 && oi1 < i1)) {
            if (b1 > ob2 || (b1 == ob2 && i1 < oi2)) { b2 = b1; i2 = i1; }
            else                                     { b2 = ob2; i2 = oi2; }
            b1 = ob1; i1 = oi1;
        } else {
            if (ob1 > b2 || (ob1 == b2 && oi1 < i2)) { b2 = ob1; i2 = oi1; }
        }
    }
    const float m = b1;   // top-1 value is the row max

    float e[16];
    float s = 0.f;
    #pragma unroll
    for (int j = 0; j < 16; ++j) { e[j] = __expf(v[j] - m); s += e[j]; }
    s += __shfl_xor(s, 1);
    s += __shfl_xor(s, 2);
    const float inv = 1.f / s;

    if (g == 0) {
        out_idx[(size_t)tok * 2 + 0] = (float)i1;
        out_idx[(size_t)tok * 2 + 1] = (float)i2;
        out_val[(size_t)tok * 2 + 0] = inv;                    // exp(b1-m)=1
        out_val[(size_t)tok * 2 + 1] = __expf(b2 - m) * inv;
    }

    #pragma unroll
    for (int j = 0; j < 4; ++j) {
        f32x4 o;
        o[0] = e[j * 4 + 0] * inv;
        o[1] = e[j * 4 + 1] * inv;
        o[2] = e[j * 4 + 2] * inv;
        o[3] = e[j * 4 + 3] * inv;
        *(f32x4*)(src + j * 4) = o;
    }
}

extern "C" void kernel_launch(void* const* d_in, const int* in_sizes, int n_in,
                              void* d_out, int out_size, void* d_ws, size_t ws_size,
                              hipStream_t stream) {
    const float* hs = (const float*)d_in[0];
    const float* W  = (const float*)d_in[1];
    const float* b  = (const float*)d_in[2];
    float* out = (float*)d_out;
    const int nTok = in_sizes[0] / D_DIM;   // 16384

    float* logits = out + (size_t)nTok * 4;  // scores region doubles as logit accumulator
    hipMemsetAsync(logits, 0, (size_t)nTok * E_DIM * sizeof(float), stream);

    dim3 g1(nTok / TM * KSPLIT), b1(256);
    router_gemm<<<g1, b1, 0, stream>>>(hs, W, logits, nTok);

    dim3 g2(nTok / 64), b2(256);
    router_epilogue<<<g2, b2, 0, stream>>>(b, out, nTok);
}